// Round 15
// baseline (180.213 us; speedup 1.0000x reference)
//
#include <hip/hip_runtime.h>

// VectorQuantizer: z [8,64,64,64] fp32 (BCHW), embedding [8192,64] fp32.
// Outputs (concat): z_q [8,64,64,64] fp32 (BCHW), indices [32768] as fp32.
//
// R28: single-owner fusion -- finalize deleted, no atomics/election.
// R27 post-mortem: fusing via a wave0-serialized phase regressed (R21 mode);
// launch overhead is small. Gumbel gap model (codes ~ random unit vectors:
// E[gap12] ~ 0.03 >> MARGIN1) => flag rate ~2-6%, suspects ~1%. So:
//  k_merge (256 blk x 128 thr, 1 px/thread, FULLY parallel): merge 8 splits;
//    fast path (gb2 < thr) and complete-shortlist pixels rescore exactly and
//    WRITE THEIR OWN z_q GATHER inline (finalize's coalesced store pattern);
//    escalated pixels (some split's b2 >= thr) push (p | mask<<16) + their
//    shortlist seed key; write nothing.
//  k_recheck: ONE WAVE PER ESCALATED PIXEL owns it end-to-end: scans each
//    suspect split's 1024 codes (proven 512-code loop x2), combines with the
//    seed key in-register, writes idx + gather. No atomicMin, no fences.
// Tie semantics: ascending split order + strict > (fast path); exact fp32
// (d, then idx) first-min everywhere else == np argmin first-occurrence.
// Tier-1 (R19-proven, untouched): fp16 1-product, v = dot + 2 in [1,3],
// 6-bit candidate id in low mantissa bits, top-2 via med3+max, NSTAGE=128,
// 2x16KB LDS dbuf, __syncthreads 2-phase loop.
// Staging (R12): global_load_lds 16B registerless from pre-swizzled codebook.

#define NPIX 32768
#define NE   8192
#define EDIM 64
#define HW   4096
#define NSTAGE 128          // codes per LDS stage (8 subtiles of 16)
#define KSPLIT 8
#define CPS  (NE / KSPLIT)  // 1024 codes per split
#define NSTG (CPS / NSTAGE) // 8 stages per block
#define MARGIN1 6.0e-4f
#define NSET 2              // row-sets of 16 pixels per wave (PPW=32)

typedef _Float16 f16x8 __attribute__((ext_vector_type(8)));
typedef float f32x4  __attribute__((ext_vector_type(4)));

__device__ __forceinline__ short f2h_bits(float x) {
    _Float16 h = (_Float16)x;
    short s; __builtin_memcpy(&s, &h, 2); return s;
}
// map float to unsigned with same total order
__device__ __forceinline__ unsigned int order_u32(float f) {
    unsigned int s = __float_as_uint(f);
    return (s & 0x80000000u) ? ~s : (s | 0x80000000u);
}
// async global->LDS, 16B/lane; HW writes lane i at lds_base + i*16 (wave-uniform base)
__device__ __forceinline__ void gload_lds16(const void* g, void* l) {
    __builtin_amdgcn_global_load_lds(
        (const __attribute__((address_space(1))) void*)g,
        (__attribute__((address_space(3))) void*)l, 16, 0, 0);
}

// ---------------- prep (fused): codebook (swizzled fp16) + pixels ------------
// esw layout: per 64-code group, 8 combos (sub[4] x {k0,k1}) x 1KB; within
// combo, MFMA-B fragment order: slot frag_lane=(o&3)*16+code_col holds 8
// channels (16B). A 128-code stage = two consecutive groups (16KB).
__global__ __launch_bounds__(256) void k_prep(const float* __restrict__ emb,
                                              const float* __restrict__ z,
                                              float* __restrict__ e_norm,
                                              float* __restrict__ se_half,
                                              short* __restrict__ esw,
                                              float* __restrict__ zn,
                                              unsigned* __restrict__ counter) {
    if (blockIdx.x == 0 && threadIdx.x == 0) counter[0] = 0u;
    if (blockIdx.x < NE / 4) {
        // --- codebook: 1 code per wave, lane = channel ---
        const int wave = threadIdx.x >> 6;
        const int lane = threadIdx.x & 63;
        const int n = blockIdx.x * 4 + wave;
        float v = emb[n * EDIM + lane];
        float ss = v * v;
        #pragma unroll
        for (int off = 32; off; off >>= 1) ss += __shfl_xor(ss, off, 64);
        const float inv = 1.0f / fmaxf(sqrtf(ss), 1e-12f);
        const float en = v * inv;
        e_norm[n * EDIM + lane] = en;
        // swizzled fp16 write (c = lane)
        const int grp = n >> 6, cs = n & 63;
        const int sub = cs >> 4, colb = cs & 15;
        const int o = lane >> 3, j = lane & 7;     // o: khalf=o>>2, quad=o&3
        const int slot = ((o & 3) * 16 + colb) * 8 + j;
        esw[grp * 4096 + (sub * 2 + (o >> 2)) * 512 + slot] = f2h_bits(en);
        float s2 = en * en;
        #pragma unroll
        for (int off = 32; off; off >>= 1) s2 += __shfl_xor(s2, off, 64);
        if (lane == 0) se_half[n] = 0.5f * s2;
    } else {
        // --- pixels: single-pass normalize -> zn fp32 row-major [p][c] ---
        const int p = (blockIdx.x - NE / 4) * 256 + threadIdx.x;
        const int b = p >> 12, hw = p & (HW - 1);
        const float* zp = z + b * (EDIM * HW) + hw;
        float v[EDIM];
        #pragma unroll
        for (int c = 0; c < EDIM; ++c) v[c] = zp[c * HW];
        float ss = 0.0f;
        #pragma unroll
        for (int c = 0; c < EDIM; ++c) ss = fmaf(v[c], v[c], ss);
        const float inv = 1.0f / fmaxf(sqrtf(ss), 1e-12f);
        #pragma unroll
        for (int c4 = 0; c4 < 16; ++c4) {
            float4 o;
            o.x = v[c4 * 4 + 0] * inv;
            o.y = v[c4 * 4 + 1] * inv;
            o.z = v[c4 * 4 + 2] * inv;
            o.w = v[c4 * 4 + 3] * inv;
            *(float4*)(zn + p * EDIM + c4 * 4) = o;
        }
    }
}

// ---------------- tier-1 k_mfma: split-K partial top-2 (R19 proven) ---------
// Block: 4 waves x 32 pixels = 128 pixels, one codebook eighth (blockIdx.y).
// v = dot + 2 in [1,3]; argmin dist == argmax v (unit vectors). Low 6 mantissa
// bits carry the candidate id (stage*8+sub). Layouts (HW-verified):
// A[m=lane&15][k=quad*8+j], B[k=quad*8+j][n=lane&15], C/D row=(lane>>4)*4+reg,
// col=lane&15.
__global__ __launch_bounds__(256, 1) void k_mfma(const float* __restrict__ zn,
                                                 const short* __restrict__ esw,
                                                 float2* __restrict__ pv,   // [g][p] {b1,b2} (max-space)
                                                 unsigned* __restrict__ pi) // [g][p] i1
{
    __shared__ __align__(16) short es[2][NSTAGE * EDIM];   // 2 x 16KB

    const int tid  = threadIdx.x;             // 0..255
    const int wave = tid >> 6, lane = tid & 63;
    const int quad = lane >> 4, col = lane & 15;
    const int p0   = blockIdx.x * 128 + wave * 32;  // wave's 32 pixels (2 sets)
    const int g    = blockIdx.y;                    // codebook eighth
    const int kbase = g * CPS;

    // A fragments: 2 sets of 16 pixels; fp32 zn -> fp16 (single product)
    f16x8 ah[NSET][2];
    #pragma unroll
    for (int s = 0; s < NSET; ++s) {
        const float* zr = zn + (p0 + s * 16 + col) * EDIM;
        #pragma unroll
        for (int kc = 0; kc < 2; ++kc) {
            float f[8];
            *(float4*)(f + 0) = *(const float4*)(zr + kc * 32 + quad * 8 + 0);
            *(float4*)(f + 4) = *(const float4*)(zr + kc * 32 + quad * 8 + 4);
            #pragma unroll
            for (int i = 0; i < 8; ++i) ah[s][kc][i] = (_Float16)f[i];
        }
    }

    // top-2 state in max-space; values stuffed with 6-bit id; b1 >= b2 invariant
    float b1[NSET][4], b2[NSET][4];
    #pragma unroll
    for (int s = 0; s < NSET; ++s)
        #pragma unroll
        for (int r = 0; r < 4; ++r) { b1[s][r] = 0.0f; b2[s][r] = 0.0f; }

    const f32x4 cini = {2.0f, 2.0f, 2.0f, 2.0f};   // |z|=|e|=1 -> bias constant

    // this wave's staging window: src and dst are both uniform + lane*16
    const int combo0 = wave * 4;   // 16 combos x 1KB per 16KB stage
    const char* gsrc0 = (const char*)esw + (size_t)kbase * 128
                        + combo0 * 1024 + lane * 16;
    // prologue: issue stage 0 -> buf 0
    #pragma unroll
    for (int it = 0; it < 4; ++it)
        gload_lds16(gsrc0 + it * 1024, (char*)&es[0][0] + (combo0 + it) * 1024);

    for (int nb = 0; nb < NSTG; ++nb) {
        const int cur = nb & 1;
        __syncthreads();   // vmcnt drained: buf[cur] complete; buf[cur^1] reusable
        if (nb + 1 < NSTG) {
            const char* gsrc = gsrc0 + (size_t)(nb + 1) * (NSTAGE * EDIM * 2);
            #pragma unroll
            for (int it = 0; it < 4; ++it)
                gload_lds16(gsrc + it * 1024,
                            (char*)&es[cur ^ 1][0] + (combo0 + it) * 1024);
        }

        const short* esb = es[cur];
        #pragma unroll
        for (int sub = 0; sub < 8; ++sub) {       // 8 subtiles of 16 codes
            const short* base = esb + sub * 1024;
            const f16x8 bh0 = *(const f16x8*)(base + lane * 8);
            const f16x8 bh1 = *(const f16x8*)(base + 512 + lane * 8);
            const unsigned sid = (unsigned)((nb << 3) | sub);  // 6-bit id, uniform
            #pragma unroll
            for (int s = 0; s < NSET; ++s) {
                // 2-deep chain seeded with C = {2.0}
                f32x4 acc;
                acc = __builtin_amdgcn_mfma_f32_16x16x32_f16(ah[s][0], bh0, cini, 0, 0, 0);
                acc = __builtin_amdgcn_mfma_f32_16x16x32_f16(ah[s][1], bh1, acc, 0, 0, 0);
                #pragma unroll
                for (int r = 0; r < 4; ++r) {
                    // stuff candidate id into low mantissa bits (v_and_or_b32)
                    const float v = __uint_as_float(
                        (__float_as_uint(acc[r]) & 0xFFFFFFC0u) | sid);
                    // b1>=b2 invariant -> med3 == new 2nd-max; then running max
                    b2[s][r] = __builtin_amdgcn_fmed3f(v, b2[s][r], b1[s][r]);
                    b1[s][r] = fmaxf(b1[s][r], v);
                }
            }
        }
    }

    // recover winning index from b1's stuffed id (col is lane-implicit)
    int i1[NSET][4];
    #pragma unroll
    for (int s = 0; s < NSET; ++s)
        #pragma unroll
        for (int r = 0; r < 4; ++r) {
            const unsigned id6 = __float_as_uint(b1[s][r]) & 63u;
            i1[s][r] = kbase + (int)(id6 << 4) + col;
        }

    // merge top-2 across the 16 col-lanes (xor 1,2,4,8 stays inside quad group)
    #pragma unroll
    for (int m = 1; m <= 8; m <<= 1) {
        #pragma unroll
        for (int s = 0; s < NSET; ++s)
            #pragma unroll
            for (int r = 0; r < 4; ++r) {
                const float ob1 = __shfl_xor(b1[s][r], m, 64);
                const int   oi1 = __shfl_xor(i1[s][r], m, 64);
                const float ob2 = __shfl_xor(b2[s][r], m, 64);
                const bool take = (ob1 > b1[s][r]) || (ob1 == b1[s][r] && oi1 < i1[s][r]);
                b2[s][r] = fmaxf(fmaxf(b2[s][r], ob2), fminf(b1[s][r], ob1));
                b1[s][r] = take ? ob1 : b1[s][r];
                i1[s][r] = take ? oi1 : i1[s][r];
            }
    }
    if (col == 0) {
        #pragma unroll
        for (int s = 0; s < NSET; ++s)
            #pragma unroll
            for (int r = 0; r < 4; ++r) {
                const int p = p0 + s * 16 + quad * 4 + r;   // C/D row = quad*4 + r
                pv[g * NPIX + p] = make_float2(b1[s][r], b2[s][r]);
                pi[g * NPIX + p] = (unsigned)i1[s][r];
            }
    }
}

// ---------------- merge: combine splits; rescore; gather; enqueue suspects ---
// 1 px/thread, 256 blocks x 128 threads (full CU coverage). Resolved pixels
// write idx + z_q gather inline (coalesced per channel: consecutive threads
// = consecutive hw). Escalated pixels push (p | mask<<16) + seed key.
__global__ __launch_bounds__(128) void k_merge(const float2* __restrict__ pv,
                                               const unsigned* __restrict__ pi,
                                               const float* __restrict__ zn,
                                               const float* __restrict__ e_norm,
                                               const float* __restrict__ se_half,
                                               unsigned* __restrict__ list,
                                               unsigned long long* __restrict__ lkey,
                                               unsigned* __restrict__ counter,
                                               float* __restrict__ out) {
    const int p = blockIdx.x * 128 + threadIdx.x;
    float2 v[KSPLIT]; unsigned ix[KSPLIT];
    #pragma unroll
    for (int gg = 0; gg < KSPLIT; ++gg) {
        v[gg] = pv[gg * NPIX + p];
        ix[gg] = pi[gg * NPIX + p];
    }
    // global noisy top-1 (ascending g + strict > == first-occurrence)
    float gb1 = v[0].x; unsigned gi1 = ix[0]; int win = 0;
    #pragma unroll
    for (int gg = 1; gg < KSPLIT; ++gg)
        if (v[gg].x > gb1) { gb1 = v[gg].x; gi1 = ix[gg]; win = gg; }
    float gb2 = -3.0e38f;
    #pragma unroll
    for (int gg = 0; gg < KSPLIT; ++gg) {
        gb2 = fmaxf(gb2, v[gg].y);
        if (gg != win) gb2 = fmaxf(gb2, v[gg].x);
    }
    const float thr = gb1 - MARGIN1;
    int bidx;
    if (gb2 < thr) {                      // clear winner (~94-98% of pixels)
        bidx = (int)gi1;
    } else {
        // exact fp32 rescore of the shortlist {i1[g] : b1[g] >= thr}
        float zr[EDIM];
        #pragma unroll
        for (int c4 = 0; c4 < 16; ++c4)
            *(float4*)(zr + c4 * 4) =
                *(const float4*)(zn + (size_t)p * EDIM + c4 * 4);
        float best = 3.0e38f; bidx = 0x7FFFFFFF;
        #pragma unroll
        for (int gg = 0; gg < KSPLIT; ++gg) {
            if (v[gg].x >= thr) {
                const int c = (int)ix[gg];
                const float* er = e_norm + (size_t)c * EDIM;
                float s = 0.0f;
                #pragma unroll
                for (int k = 0; k < EDIM; ++k) s = fmaf(zr[k], er[k], s);
                const float d = se_half[c] - s;
                if (d < best || (d == best && c < bidx)) { best = d; bidx = c; }
            }
        }
        // suspect splits: untracked codes can hide only where b2 >= thr
        unsigned mask = 0;
        #pragma unroll
        for (int gg = 0; gg < KSPLIT; ++gg)
            if (v[gg].y >= thr) mask |= (1u << gg);
        if (mask) {                        // escalate: owner wave finishes it
            const unsigned pos = atomicAdd(&counter[0], 1u);
            list[pos] = (unsigned)p | (mask << 16);
            lkey[pos] = ((unsigned long long)order_u32(best) << 32) | (unsigned)bidx;
            return;                        // no output writes
        }
    }
    // write idx + z_q gather (coalesced per channel across the wave)
    out[NPIX * EDIM + p] = (float)bidx;
    const int b = p >> 12, hw = p & (HW - 1);
    float* op = out + b * (EDIM * HW) + hw;
    const float4* ep4 = (const float4*)(e_norm + (size_t)bidx * EDIM);
    #pragma unroll
    for (int j = 0; j < 16; ++j) {
        const float4 e = ep4[j];
        const int c = j * 4;
        op[(c + 0) * HW] = e.x; op[(c + 1) * HW] = e.y;
        op[(c + 2) * HW] = e.z; op[(c + 3) * HW] = e.w;
    }
}

// ---------------- recheck: one wave owns each escalated pixel ----------------
// Scans each suspect split's 1024 codes (2x 512-code chunks, proven loop),
// combines with the seed key in-register, writes idx + gather. No atomics.
__global__ __launch_bounds__(256) void k_recheck(const float* __restrict__ zn,
                                                 const float* __restrict__ e_norm,
                                                 const float* __restrict__ se_half,
                                                 const unsigned* __restrict__ list,
                                                 const unsigned long long* __restrict__ lkey,
                                                 const unsigned* __restrict__ counter,
                                                 float* __restrict__ out) {
    const int lane  = threadIdx.x & 63;
    const int k     = lane >> 4;        // code-in-group 0..3
    const int m     = lane & 15;        // c4 index 0..15
    const int wglob = (blockIdx.x * 256 + threadIdx.x) >> 6;
    const int nwav  = (gridDim.x * 256) >> 6;
    int cnt = (int)counter[0]; if (cnt > NPIX) cnt = NPIX;
    const float4* e4 = (const float4*)e_norm;

    for (int item = wglob; item < cnt; item += nwav) {
        const unsigned e = list[item];
        const int p = (int)(e & 0xFFFFu);
        const unsigned mask = e >> 16;
        unsigned long long key = lkey[item];
        const float4 zv = *(const float4*)(zn + (size_t)p * EDIM + m * 4);
        for (int g = 0; g < KSPLIT; ++g) {
            if (!(mask & (1u << g))) continue;
            #pragma unroll
            for (int half = 0; half < 2; ++half) {
                const int chunk = g * 2 + half;
                float best = 3.0e38f; int bidx = 0;
                for (int t4 = 0; t4 < 32; ++t4) {          // 16 codes per iter
                    float s[4]; int n[4];
                    #pragma unroll
                    for (int j = 0; j < 4; ++j) {
                        n[j] = chunk * 512 + (t4 * 4 + j) * 4 + k;
                        const float4 ev = e4[n[j] * 16 + m];
                        s[j] = fmaf(zv.w, ev.w, fmaf(zv.z, ev.z,
                               fmaf(zv.y, ev.y, zv.x * ev.x)));
                    }
                    #pragma unroll
                    for (int j = 0; j < 4; ++j) s[j] += __shfl_xor(s[j], 1, 64);
                    #pragma unroll
                    for (int j = 0; j < 4; ++j) s[j] += __shfl_xor(s[j], 2, 64);
                    #pragma unroll
                    for (int j = 0; j < 4; ++j) s[j] += __shfl_xor(s[j], 4, 64);
                    #pragma unroll
                    for (int j = 0; j < 4; ++j) s[j] += __shfl_xor(s[j], 8, 64);
                    #pragma unroll
                    for (int j = 0; j < 4; ++j) {          // codes ascend
                        const float d = se_half[n[j]] - s[j];
                        if (d < best) { best = d; bidx = n[j]; }
                    }
                }
                #pragma unroll
                for (int mm = 1; mm <= 32; mm <<= 1) {     // wave first-min
                    const float ob = __shfl_xor(best, mm, 64);
                    const int   oi = __shfl_xor(bidx, mm, 64);
                    if (ob < best || (ob == best && oi < bidx)) { best = ob; bidx = oi; }
                }
                const unsigned long long kk =                // uniform on wave
                    ((unsigned long long)order_u32(best) << 32) | (unsigned)bidx;
                key = (kk < key) ? kk : key;
            }
        }
        // owner write: idx + gather (lane = channel)
        const int bidx = (int)(key & 0xFFFFFFFFull);
        if (lane == 0) out[NPIX * EDIM + p] = (float)bidx;
        const int b = p >> 12, hw = p & (HW - 1);
        out[b * (EDIM * HW) + lane * HW + hw] = e_norm[(size_t)bidx * EDIM + lane];
    }
}

extern "C" void kernel_launch(void* const* d_in, const int* in_sizes, int n_in,
                              void* d_out, int out_size, void* d_ws, size_t ws_size,
                              hipStream_t stream) {
    const float* z   = (const float*)d_in[0];
    const float* emb = (const float*)d_in[1];
    float* out = (float*)d_out;

    // workspace layout (~14.5 MB)
    float* e_norm  = (float*)d_ws;                       // 2 MB
    float* se_half = e_norm + NE * EDIM;                 // 32 KB
    short* esw = (short*)(se_half + NE);                 // 1 MB (swizzled fp16)
    float* zn = (float*)(esw + NE * EDIM);               // 8 MB
    unsigned* list    = (unsigned*)(zn + NPIX * EDIM);   // 128 KB (escalated)
    unsigned* counter = list + NPIX;                     // 4 B (+pad)
    unsigned long long* lkey = (unsigned long long*)(counter + 64); // 256 KB
    float2*   pv = (float2*)(lkey + NPIX);               // 2 MB
    unsigned* pi = (unsigned*)(pv + KSPLIT * NPIX);      // 1 MB

    k_prep<<<NE / 4 + NPIX / 256, 256, 0, stream>>>(emb, z, e_norm, se_half,
                                                    esw, zn, counter);
    k_mfma<<<dim3(NPIX / 128, KSPLIT), 256, 0, stream>>>(zn, esw, pv, pi);
    k_merge<<<NPIX / 128, 128, 0, stream>>>(pv, pi, zn, e_norm, se_half,
                                            list, lkey, counter, out);
    k_recheck<<<256, 256, 0, stream>>>(zn, e_norm, se_half, list, lkey,
                                       counter, out);
}

// Round 16
// 177.896 us; speedup vs baseline: 1.0130x; 1.0130x over previous
//
#include <hip/hip_runtime.h>

// VectorQuantizer: z [8,64,64,64] fp32 (BCHW), embedding [8192,64] fp32.
// Outputs (concat): z_q [8,64,64,64] fp32 (BCHW), indices [32768] as fp32.
//
// R29: merge+finalize fused as k_mf -- 5 -> 4 kernels, NO proven-pattern
// violations. R27 failed (wave0-serial merge); R28 failed (zr[64] register
// blowup + 64 stores/thread + divergence holes in its fused merge). k_mf:
//  - 4 threads/pixel (512 blk x 256 thr), finalize's exact parallel shape.
//  - All 4 threads redundantly merge the 8 split top-2s (pv/pi read x4,
//    ~+9MB L2 traffic; no cross-thread handoff needed for fast path).
//  - Flagged pixels: shortlist {i1[g] : b1[g] >= thr} rescored in exact
//    fp32 SPLIT ACROSS the 4 threads (16 channels each) -> LDS partials
//    (padded [4][64][9]) -> one unconditional __syncthreads -> all 4
//    combine identically. Static 8-slot indexing (no compaction arrays).
//  - Escalated (some split b2 >= thr): q==0 pushes (p | mask<<16) + exact
//    seed key; output written later by k_recheck (R28's owner-wave form,
//    which was fine). Everyone else gathers z_q in place (proven pattern).
// Tie semantics: ascending split order + strict > (fast path); exact fp32
// (d, then idx) first-min for rescore/scan == np argmin first-occurrence.
// Tier-1 (R19-proven, byte-identical, VGPR 64 -- the 64-VGPR occupancy step
// is why R24's +b3/+i2 version cost +20us): fp16 1-product, v = dot + 2,
// 6-bit mantissa id, top-2 via med3+max, NSTAGE=128, 2x16KB LDS dbuf.
// Staging (R12): global_load_lds 16B registerless from pre-swizzled codebook.

#define NPIX 32768
#define NE   8192
#define EDIM 64
#define HW   4096
#define NSTAGE 128          // codes per LDS stage (8 subtiles of 16)
#define KSPLIT 8
#define CPS  (NE / KSPLIT)  // 1024 codes per split
#define NSTG (CPS / NSTAGE) // 8 stages per block
#define MARGIN1 6.0e-4f
#define NSET 2              // row-sets of 16 pixels per wave (PPW=32)

typedef _Float16 f16x8 __attribute__((ext_vector_type(8)));
typedef float f32x4  __attribute__((ext_vector_type(4)));

__device__ __forceinline__ short f2h_bits(float x) {
    _Float16 h = (_Float16)x;
    short s; __builtin_memcpy(&s, &h, 2); return s;
}
// map float to unsigned with same total order
__device__ __forceinline__ unsigned int order_u32(float f) {
    unsigned int s = __float_as_uint(f);
    return (s & 0x80000000u) ? ~s : (s | 0x80000000u);
}
// async global->LDS, 16B/lane; HW writes lane i at lds_base + i*16 (wave-uniform base)
__device__ __forceinline__ void gload_lds16(const void* g, void* l) {
    __builtin_amdgcn_global_load_lds(
        (const __attribute__((address_space(1))) void*)g,
        (__attribute__((address_space(3))) void*)l, 16, 0, 0);
}

// ---------------- prep (fused): codebook (swizzled fp16) + pixels ------------
// esw layout: per 64-code group, 8 combos (sub[4] x {k0,k1}) x 1KB; within
// combo, MFMA-B fragment order: slot frag_lane=(o&3)*16+code_col holds 8
// channels (16B). A 128-code stage = two consecutive groups (16KB).
__global__ __launch_bounds__(256) void k_prep(const float* __restrict__ emb,
                                              const float* __restrict__ z,
                                              float* __restrict__ e_norm,
                                              float* __restrict__ se_half,
                                              short* __restrict__ esw,
                                              float* __restrict__ zn,
                                              unsigned* __restrict__ counter) {
    if (blockIdx.x == 0 && threadIdx.x == 0) counter[0] = 0u;
    if (blockIdx.x < NE / 4) {
        // --- codebook: 1 code per wave, lane = channel ---
        const int wave = threadIdx.x >> 6;
        const int lane = threadIdx.x & 63;
        const int n = blockIdx.x * 4 + wave;
        float v = emb[n * EDIM + lane];
        float ss = v * v;
        #pragma unroll
        for (int off = 32; off; off >>= 1) ss += __shfl_xor(ss, off, 64);
        const float inv = 1.0f / fmaxf(sqrtf(ss), 1e-12f);
        const float en = v * inv;
        e_norm[n * EDIM + lane] = en;
        // swizzled fp16 write (c = lane)
        const int grp = n >> 6, cs = n & 63;
        const int sub = cs >> 4, colb = cs & 15;
        const int o = lane >> 3, j = lane & 7;     // o: khalf=o>>2, quad=o&3
        const int slot = ((o & 3) * 16 + colb) * 8 + j;
        esw[grp * 4096 + (sub * 2 + (o >> 2)) * 512 + slot] = f2h_bits(en);
        float s2 = en * en;
        #pragma unroll
        for (int off = 32; off; off >>= 1) s2 += __shfl_xor(s2, off, 64);
        if (lane == 0) se_half[n] = 0.5f * s2;
    } else {
        // --- pixels: single-pass normalize -> zn fp32 row-major [p][c] ---
        const int p = (blockIdx.x - NE / 4) * 256 + threadIdx.x;
        const int b = p >> 12, hw = p & (HW - 1);
        const float* zp = z + b * (EDIM * HW) + hw;
        float v[EDIM];
        #pragma unroll
        for (int c = 0; c < EDIM; ++c) v[c] = zp[c * HW];
        float ss = 0.0f;
        #pragma unroll
        for (int c = 0; c < EDIM; ++c) ss = fmaf(v[c], v[c], ss);
        const float inv = 1.0f / fmaxf(sqrtf(ss), 1e-12f);
        #pragma unroll
        for (int c4 = 0; c4 < 16; ++c4) {
            float4 o;
            o.x = v[c4 * 4 + 0] * inv;
            o.y = v[c4 * 4 + 1] * inv;
            o.z = v[c4 * 4 + 2] * inv;
            o.w = v[c4 * 4 + 3] * inv;
            *(float4*)(zn + p * EDIM + c4 * 4) = o;
        }
    }
}

// ---------------- tier-1 k_mfma: split-K partial top-2 (R19 proven) ---------
// Block: 4 waves x 32 pixels = 128 pixels, one codebook eighth (blockIdx.y).
// v = dot + 2 in [1,3]; argmin dist == argmax v (unit vectors). Low 6 mantissa
// bits carry the candidate id (stage*8+sub). Layouts (HW-verified):
// A[m=lane&15][k=quad*8+j], B[k=quad*8+j][n=lane&15], C/D row=(lane>>4)*4+reg,
// col=lane&15.
__global__ __launch_bounds__(256, 1) void k_mfma(const float* __restrict__ zn,
                                                 const short* __restrict__ esw,
                                                 float2* __restrict__ pv,   // [g][p] {b1,b2} (max-space)
                                                 unsigned* __restrict__ pi) // [g][p] i1
{
    __shared__ __align__(16) short es[2][NSTAGE * EDIM];   // 2 x 16KB

    const int tid  = threadIdx.x;             // 0..255
    const int wave = tid >> 6, lane = tid & 63;
    const int quad = lane >> 4, col = lane & 15;
    const int p0   = blockIdx.x * 128 + wave * 32;  // wave's 32 pixels (2 sets)
    const int g    = blockIdx.y;                    // codebook eighth
    const int kbase = g * CPS;

    // A fragments: 2 sets of 16 pixels; fp32 zn -> fp16 (single product)
    f16x8 ah[NSET][2];
    #pragma unroll
    for (int s = 0; s < NSET; ++s) {
        const float* zr = zn + (p0 + s * 16 + col) * EDIM;
        #pragma unroll
        for (int kc = 0; kc < 2; ++kc) {
            float f[8];
            *(float4*)(f + 0) = *(const float4*)(zr + kc * 32 + quad * 8 + 0);
            *(float4*)(f + 4) = *(const float4*)(zr + kc * 32 + quad * 8 + 4);
            #pragma unroll
            for (int i = 0; i < 8; ++i) ah[s][kc][i] = (_Float16)f[i];
        }
    }

    // top-2 state in max-space; values stuffed with 6-bit id; b1 >= b2 invariant
    float b1[NSET][4], b2[NSET][4];
    #pragma unroll
    for (int s = 0; s < NSET; ++s)
        #pragma unroll
        for (int r = 0; r < 4; ++r) { b1[s][r] = 0.0f; b2[s][r] = 0.0f; }

    const f32x4 cini = {2.0f, 2.0f, 2.0f, 2.0f};   // |z|=|e|=1 -> bias constant

    // this wave's staging window: src and dst are both uniform + lane*16
    const int combo0 = wave * 4;   // 16 combos x 1KB per 16KB stage
    const char* gsrc0 = (const char*)esw + (size_t)kbase * 128
                        + combo0 * 1024 + lane * 16;
    // prologue: issue stage 0 -> buf 0
    #pragma unroll
    for (int it = 0; it < 4; ++it)
        gload_lds16(gsrc0 + it * 1024, (char*)&es[0][0] + (combo0 + it) * 1024);

    for (int nb = 0; nb < NSTG; ++nb) {
        const int cur = nb & 1;
        __syncthreads();   // vmcnt drained: buf[cur] complete; buf[cur^1] reusable
        if (nb + 1 < NSTG) {
            const char* gsrc = gsrc0 + (size_t)(nb + 1) * (NSTAGE * EDIM * 2);
            #pragma unroll
            for (int it = 0; it < 4; ++it)
                gload_lds16(gsrc + it * 1024,
                            (char*)&es[cur ^ 1][0] + (combo0 + it) * 1024);
        }

        const short* esb = es[cur];
        #pragma unroll
        for (int sub = 0; sub < 8; ++sub) {       // 8 subtiles of 16 codes
            const short* base = esb + sub * 1024;
            const f16x8 bh0 = *(const f16x8*)(base + lane * 8);
            const f16x8 bh1 = *(const f16x8*)(base + 512 + lane * 8);
            const unsigned sid = (unsigned)((nb << 3) | sub);  // 6-bit id, uniform
            #pragma unroll
            for (int s = 0; s < NSET; ++s) {
                // 2-deep chain seeded with C = {2.0}
                f32x4 acc;
                acc = __builtin_amdgcn_mfma_f32_16x16x32_f16(ah[s][0], bh0, cini, 0, 0, 0);
                acc = __builtin_amdgcn_mfma_f32_16x16x32_f16(ah[s][1], bh1, acc, 0, 0, 0);
                #pragma unroll
                for (int r = 0; r < 4; ++r) {
                    // stuff candidate id into low mantissa bits (v_and_or_b32)
                    const float v = __uint_as_float(
                        (__float_as_uint(acc[r]) & 0xFFFFFFC0u) | sid);
                    // b1>=b2 invariant -> med3 == new 2nd-max; then running max
                    b2[s][r] = __builtin_amdgcn_fmed3f(v, b2[s][r], b1[s][r]);
                    b1[s][r] = fmaxf(b1[s][r], v);
                }
            }
        }
    }

    // recover winning index from b1's stuffed id (col is lane-implicit)
    int i1[NSET][4];
    #pragma unroll
    for (int s = 0; s < NSET; ++s)
        #pragma unroll
        for (int r = 0; r < 4; ++r) {
            const unsigned id6 = __float_as_uint(b1[s][r]) & 63u;
            i1[s][r] = kbase + (int)(id6 << 4) + col;
        }

    // merge top-2 across the 16 col-lanes (xor 1,2,4,8 stays inside quad group)
    #pragma unroll
    for (int m = 1; m <= 8; m <<= 1) {
        #pragma unroll
        for (int s = 0; s < NSET; ++s)
            #pragma unroll
            for (int r = 0; r < 4; ++r) {
                const float ob1 = __shfl_xor(b1[s][r], m, 64);
                const int   oi1 = __shfl_xor(i1[s][r], m, 64);
                const float ob2 = __shfl_xor(b2[s][r], m, 64);
                const bool take = (ob1 > b1[s][r]) || (ob1 == b1[s][r] && oi1 < i1[s][r]);
                b2[s][r] = fmaxf(fmaxf(b2[s][r], ob2), fminf(b1[s][r], ob1));
                b1[s][r] = take ? ob1 : b1[s][r];
                i1[s][r] = take ? oi1 : i1[s][r];
            }
    }
    if (col == 0) {
        #pragma unroll
        for (int s = 0; s < NSET; ++s)
            #pragma unroll
            for (int r = 0; r < 4; ++r) {
                const int p = p0 + s * 16 + quad * 4 + r;   // C/D row = quad*4 + r
                pv[g * NPIX + p] = make_float2(b1[s][r], b2[s][r]);
                pi[g * NPIX + p] = (unsigned)i1[s][r];
            }
    }
}

// ---------------- k_mf: merge + shortlist rescore + finalize (fused) ---------
// 512 blocks x 256 thr, 4 threads/pixel (q = channel quarter, pl = pixel).
// All 4 threads merge redundantly; flagged pixels rescore the shortlist with
// per-quarter partial dots through LDS (one unconditional barrier); escalated
// pixels (suspect mask) are deferred to k_recheck. Gather = proven pattern.
__global__ __launch_bounds__(256) void k_mf(const float2* __restrict__ pv,
                                            const unsigned* __restrict__ pi,
                                            const float* __restrict__ zn,
                                            const float* __restrict__ e_norm,
                                            const float* __restrict__ se_half,
                                            unsigned* __restrict__ list,
                                            unsigned long long* __restrict__ lkey,
                                            unsigned* __restrict__ counter,
                                            float* __restrict__ out) {
    __shared__ float s_part[4][64][9];     // padded: bank-conflict-free

    const int tid = threadIdx.x;
    const int q   = tid >> 6, pl = tid & 63;
    const int p   = blockIdx.x * 64 + pl;

    float2 v[KSPLIT]; unsigned ix[KSPLIT];
    #pragma unroll
    for (int gg = 0; gg < KSPLIT; ++gg) {
        v[gg] = pv[gg * NPIX + p];
        ix[gg] = pi[gg * NPIX + p];
    }
    // global noisy top-1 (ascending g + strict > == first-occurrence)
    float gb1 = v[0].x; unsigned gi1 = ix[0]; int win = 0;
    #pragma unroll
    for (int gg = 1; gg < KSPLIT; ++gg)
        if (v[gg].x > gb1) { gb1 = v[gg].x; gi1 = ix[gg]; win = gg; }
    float gb2 = -3.0e38f;
    #pragma unroll
    for (int gg = 0; gg < KSPLIT; ++gg) {
        gb2 = fmaxf(gb2, v[gg].y);
        if (gg != win) gb2 = fmaxf(gb2, v[gg].x);
    }
    const float thr = gb1 - MARGIN1;
    const bool flagged = !(gb2 < thr);

    // flagged: per-quarter partial dots for the (static 8-slot) shortlist
    if (flagged) {
        const float4* zq = (const float4*)(zn + (size_t)p * EDIM + q * 16);
        const float4 z0 = zq[0], z1 = zq[1], z2 = zq[2], z3 = zq[3];
        #pragma unroll
        for (int gg = 0; gg < KSPLIT; ++gg) {
            float s = 0.0f;
            if (v[gg].x >= thr) {
                const float4* er = (const float4*)(e_norm + (size_t)ix[gg] * EDIM + q * 16);
                const float4 e0 = er[0], e1 = er[1], e2 = er[2], e3 = er[3];
                s = fmaf(z0.x, e0.x, fmaf(z0.y, e0.y, fmaf(z0.z, e0.z, z0.w * e0.w)));
                s = fmaf(z1.x, e1.x, fmaf(z1.y, e1.y, fmaf(z1.z, e1.z, fmaf(z1.w, e1.w, s))));
                s = fmaf(z2.x, e2.x, fmaf(z2.y, e2.y, fmaf(z2.z, e2.z, fmaf(z2.w, e2.w, s))));
                s = fmaf(z3.x, e3.x, fmaf(z3.y, e3.y, fmaf(z3.z, e3.z, fmaf(z3.w, e3.w, s))));
            }
            s_part[q][pl][gg] = s;
        }
    }
    __syncthreads();                        // unconditional (uniform)

    int bidx = (int)gi1;
    unsigned mask = 0;
    if (flagged) {
        float best = 3.0e38f; int bb = 0x7FFFFFFF;
        #pragma unroll
        for (int gg = 0; gg < KSPLIT; ++gg) {
            if (v[gg].x >= thr) {
                const float s = s_part[0][pl][gg] + s_part[1][pl][gg]
                              + s_part[2][pl][gg] + s_part[3][pl][gg];
                const int c = (int)ix[gg];
                const float d = se_half[c] - s;
                if (d < best || (d == best && c < bb)) { best = d; bb = c; }
            }
        }
        bidx = bb;
        // suspect splits: untracked codes can hide only where b2 >= thr
        #pragma unroll
        for (int gg = 0; gg < KSPLIT; ++gg)
            if (v[gg].y >= thr) mask |= (1u << gg);
        if (mask && q == 0) {               // escalate: owner wave finishes it
            const unsigned pos = atomicAdd(&counter[0], 1u);
            list[pos] = (unsigned)p | (mask << 16);
            lkey[pos] = ((unsigned long long)order_u32(best) << 32) | (unsigned)bb;
        }
    }
    if (mask) return;                       // escalated: no output writes

    // write idx + z_q gather (proven 4-thr/pixel coalesced pattern)
    if (q == 0) out[NPIX * EDIM + p] = (float)bidx;
    const int b = p >> 12, hw = p & (HW - 1);
    float* op = out + b * (EDIM * HW) + hw;
    const float4* ep4 = (const float4*)(e_norm + (size_t)bidx * EDIM + q * 16);
    #pragma unroll
    for (int j = 0; j < 4; ++j) {
        const float4 e = ep4[j];
        const int c = q * 16 + j * 4;
        op[(c + 0) * HW] = e.x; op[(c + 1) * HW] = e.y;   // coalesced per c
        op[(c + 2) * HW] = e.z; op[(c + 3) * HW] = e.w;
    }
}

// ---------------- recheck: one wave owns each escalated pixel ----------------
// Scans each suspect split's 1024 codes (2x 512-code chunks, proven loop),
// combines with the seed key in-register, writes idx + gather. No atomics.
__global__ __launch_bounds__(256) void k_recheck(const float* __restrict__ zn,
                                                 const float* __restrict__ e_norm,
                                                 const float* __restrict__ se_half,
                                                 const unsigned* __restrict__ list,
                                                 const unsigned long long* __restrict__ lkey,
                                                 const unsigned* __restrict__ counter,
                                                 float* __restrict__ out) {
    const int lane  = threadIdx.x & 63;
    const int k     = lane >> 4;        // code-in-group 0..3
    const int m     = lane & 15;        // c4 index 0..15
    const int wglob = (blockIdx.x * 256 + threadIdx.x) >> 6;
    const int nwav  = (gridDim.x * 256) >> 6;
    int cnt = (int)counter[0]; if (cnt > NPIX) cnt = NPIX;
    const float4* e4 = (const float4*)e_norm;

    for (int item = wglob; item < cnt; item += nwav) {
        const unsigned e = list[item];
        const int p = (int)(e & 0xFFFFu);
        const unsigned mask = e >> 16;
        unsigned long long key = lkey[item];
        const float4 zv = *(const float4*)(zn + (size_t)p * EDIM + m * 4);
        for (int g = 0; g < KSPLIT; ++g) {
            if (!(mask & (1u << g))) continue;
            #pragma unroll
            for (int half = 0; half < 2; ++half) {
                const int chunk = g * 2 + half;
                float best = 3.0e38f; int bidx = 0;
                for (int t4 = 0; t4 < 32; ++t4) {          // 16 codes per iter
                    float s[4]; int n[4];
                    #pragma unroll
                    for (int j = 0; j < 4; ++j) {
                        n[j] = chunk * 512 + (t4 * 4 + j) * 4 + k;
                        const float4 ev = e4[n[j] * 16 + m];
                        s[j] = fmaf(zv.w, ev.w, fmaf(zv.z, ev.z,
                               fmaf(zv.y, ev.y, zv.x * ev.x)));
                    }
                    #pragma unroll
                    for (int j = 0; j < 4; ++j) s[j] += __shfl_xor(s[j], 1, 64);
                    #pragma unroll
                    for (int j = 0; j < 4; ++j) s[j] += __shfl_xor(s[j], 2, 64);
                    #pragma unroll
                    for (int j = 0; j < 4; ++j) s[j] += __shfl_xor(s[j], 4, 64);
                    #pragma unroll
                    for (int j = 0; j < 4; ++j) s[j] += __shfl_xor(s[j], 8, 64);
                    #pragma unroll
                    for (int j = 0; j < 4; ++j) {          // codes ascend
                        const float d = se_half[n[j]] - s[j];
                        if (d < best) { best = d; bidx = n[j]; }
                    }
                }
                #pragma unroll
                for (int mm = 1; mm <= 32; mm <<= 1) {     // wave first-min
                    const float ob = __shfl_xor(best, mm, 64);
                    const int   oi = __shfl_xor(bidx, mm, 64);
                    if (ob < best || (ob == best && oi < bidx)) { best = ob; bidx = oi; }
                }
                const unsigned long long kk =                // uniform on wave
                    ((unsigned long long)order_u32(best) << 32) | (unsigned)bidx;
                key = (kk < key) ? kk : key;
            }
        }
        // owner write: idx + gather (lane = channel)
        const int bidx = (int)(key & 0xFFFFFFFFull);
        if (lane == 0) out[NPIX * EDIM + p] = (float)bidx;
        const int b = p >> 12, hw = p & (HW - 1);
        out[b * (EDIM * HW) + lane * HW + hw] = e_norm[(size_t)bidx * EDIM + lane];
    }
}

extern "C" void kernel_launch(void* const* d_in, const int* in_sizes, int n_in,
                              void* d_out, int out_size, void* d_ws, size_t ws_size,
                              hipStream_t stream) {
    const float* z   = (const float*)d_in[0];
    const float* emb = (const float*)d_in[1];
    float* out = (float*)d_out;

    // workspace layout (~14.5 MB)
    float* e_norm  = (float*)d_ws;                       // 2 MB
    float* se_half = e_norm + NE * EDIM;                 // 32 KB
    short* esw = (short*)(se_half + NE);                 // 1 MB (swizzled fp16)
    float* zn = (float*)(esw + NE * EDIM);               // 8 MB
    unsigned* list    = (unsigned*)(zn + NPIX * EDIM);   // 128 KB (escalated)
    unsigned* counter = list + NPIX;                     // 4 B (+pad)
    unsigned long long* lkey = (unsigned long long*)(counter + 64); // 256 KB
    float2*   pv = (float2*)(lkey + NPIX);               // 2 MB
    unsigned* pi = (unsigned*)(pv + KSPLIT * NPIX);      // 1 MB

    k_prep<<<NE / 4 + NPIX / 256, 256, 0, stream>>>(emb, z, e_norm, se_half,
                                                    esw, zn, counter);
    k_mfma<<<dim3(NPIX / 128, KSPLIT), 256, 0, stream>>>(zn, esw, pv, pi);
    k_mf<<<NPIX / 64, 256, 0, stream>>>(pv, pi, zn, e_norm, se_half,
                                        list, lkey, counter, out);
    k_recheck<<<256, 256, 0, stream>>>(zn, e_norm, se_half, list, lkey,
                                       counter, out);
}

// Round 17
// 162.917 us; speedup vs baseline: 1.1062x; 1.0919x over previous
//
#include <hip/hip_runtime.h>

// VectorQuantizer: z [8,64,64,64] fp32 (BCHW), embedding [8192,64] fp32.
// Outputs (concat): z_q [8,64,64,64] fp32 (BCHW), indices [32768] as fp32.
//
// R30: KSPLIT 8 -> 4 (tier-1 fixed-cost amortization).
// R27-R29 post-mortem: all three merge/finalize fusions regressed -- each
// added >= the ~10us launch saving in execution (redundant reads, register
// pressure, serialization). The 5-kernel R24-R26 ladder stands at ~165+-2.
// k_mfma's per-block fixed work (A-load + 32 cvt/thread, prologue, col-merge,
// writeback) is paid by 2048 blocks; halving block count (1024 blocks x 16
// stages, same per-stage work, same epochs/CU) halves it. Candidate id now
// needs 7 bits (16 stages x 8 subs): mask 0xFFFFFF80, truncation <= 127 ulp
// ~ 3e-5 << MARGIN1 (noise sigma ~7e-5, ~7x covered). pv/pi shrink to
// 4 x NPIX. Suspect splits cover 2048 codes -> enqueue 4 x 512-code chunks
// (R26's proven chunk scanner, unchanged).
// Tier-1 core (R19-proven): fp16 1-product, v = dot + 2 in [1,3], mantissa
// id, top-2 via med3+max, NSTAGE=128, 2x16KB LDS dbuf, __syncthreads loop.
// Staging (R12): global_load_lds 16B registerless from pre-swizzled codebook.

#define NPIX 32768
#define NE   8192
#define EDIM 64
#define HW   4096
#define NSTAGE 128          // codes per LDS stage (8 subtiles of 16)
#define KSPLIT 4
#define CPS  (NE / KSPLIT)  // 2048 codes per split
#define NSTG (CPS / NSTAGE) // 16 stages per block
#define MARGIN1 6.0e-4f
#define NSET 2              // row-sets of 16 pixels per wave (PPW=32)

typedef _Float16 f16x8 __attribute__((ext_vector_type(8)));
typedef float f32x4  __attribute__((ext_vector_type(4)));

__device__ __forceinline__ short f2h_bits(float x) {
    _Float16 h = (_Float16)x;
    short s; __builtin_memcpy(&s, &h, 2); return s;
}
// map float to unsigned with same total order
__device__ __forceinline__ unsigned int order_u32(float f) {
    unsigned int s = __float_as_uint(f);
    return (s & 0x80000000u) ? ~s : (s | 0x80000000u);
}
// async global->LDS, 16B/lane; HW writes lane i at lds_base + i*16 (wave-uniform base)
__device__ __forceinline__ void gload_lds16(const void* g, void* l) {
    __builtin_amdgcn_global_load_lds(
        (const __attribute__((address_space(1))) void*)g,
        (__attribute__((address_space(3))) void*)l, 16, 0, 0);
}

// ---------------- prep (fused): codebook (swizzled fp16) + pixels ------------
// esw layout: per 64-code group, 8 combos (sub[4] x {k0,k1}) x 1KB; within
// combo, MFMA-B fragment order: slot frag_lane=(o&3)*16+code_col holds 8
// channels (16B). A 128-code stage = two consecutive groups (16KB).
__global__ __launch_bounds__(256) void k_prep(const float* __restrict__ emb,
                                              const float* __restrict__ z,
                                              float* __restrict__ e_norm,
                                              float* __restrict__ se_half,
                                              short* __restrict__ esw,
                                              float* __restrict__ zn,
                                              unsigned* __restrict__ counter) {
    if (blockIdx.x == 0 && threadIdx.x == 0) counter[0] = 0u;
    if (blockIdx.x < NE / 4) {
        // --- codebook: 1 code per wave, lane = channel ---
        const int wave = threadIdx.x >> 6;
        const int lane = threadIdx.x & 63;
        const int n = blockIdx.x * 4 + wave;
        float v = emb[n * EDIM + lane];
        float ss = v * v;
        #pragma unroll
        for (int off = 32; off; off >>= 1) ss += __shfl_xor(ss, off, 64);
        const float inv = 1.0f / fmaxf(sqrtf(ss), 1e-12f);
        const float en = v * inv;
        e_norm[n * EDIM + lane] = en;
        // swizzled fp16 write (c = lane)
        const int grp = n >> 6, cs = n & 63;
        const int sub = cs >> 4, colb = cs & 15;
        const int o = lane >> 3, j = lane & 7;     // o: khalf=o>>2, quad=o&3
        const int slot = ((o & 3) * 16 + colb) * 8 + j;
        esw[grp * 4096 + (sub * 2 + (o >> 2)) * 512 + slot] = f2h_bits(en);
        float s2 = en * en;
        #pragma unroll
        for (int off = 32; off; off >>= 1) s2 += __shfl_xor(s2, off, 64);
        if (lane == 0) se_half[n] = 0.5f * s2;
    } else {
        // --- pixels: single-pass normalize -> zn fp32 row-major [p][c] ---
        const int p = (blockIdx.x - NE / 4) * 256 + threadIdx.x;
        const int b = p >> 12, hw = p & (HW - 1);
        const float* zp = z + b * (EDIM * HW) + hw;
        float v[EDIM];
        #pragma unroll
        for (int c = 0; c < EDIM; ++c) v[c] = zp[c * HW];
        float ss = 0.0f;
        #pragma unroll
        for (int c = 0; c < EDIM; ++c) ss = fmaf(v[c], v[c], ss);
        const float inv = 1.0f / fmaxf(sqrtf(ss), 1e-12f);
        #pragma unroll
        for (int c4 = 0; c4 < 16; ++c4) {
            float4 o;
            o.x = v[c4 * 4 + 0] * inv;
            o.y = v[c4 * 4 + 1] * inv;
            o.z = v[c4 * 4 + 2] * inv;
            o.w = v[c4 * 4 + 3] * inv;
            *(float4*)(zn + p * EDIM + c4 * 4) = o;
        }
    }
}

// ---------------- tier-1 k_mfma: split-K partial top-2 ----------------------
// Block: 4 waves x 32 pixels = 128 pixels, one codebook quarter (blockIdx.y).
// v = dot + 2 in [1,3]; argmin dist == argmax v (unit vectors). Low 7 mantissa
// bits carry the candidate id (stage*8+sub, 16 stages). Layouts (HW-verified):
// A[m=lane&15][k=quad*8+j], B[k=quad*8+j][n=lane&15], C/D row=(lane>>4)*4+reg,
// col=lane&15.
__global__ __launch_bounds__(256, 1) void k_mfma(const float* __restrict__ zn,
                                                 const short* __restrict__ esw,
                                                 float2* __restrict__ pv,   // [g][p] {b1,b2} (max-space)
                                                 unsigned* __restrict__ pi) // [g][p] i1
{
    __shared__ __align__(16) short es[2][NSTAGE * EDIM];   // 2 x 16KB

    const int tid  = threadIdx.x;             // 0..255
    const int wave = tid >> 6, lane = tid & 63;
    const int quad = lane >> 4, col = lane & 15;
    const int p0   = blockIdx.x * 128 + wave * 32;  // wave's 32 pixels (2 sets)
    const int g    = blockIdx.y;                    // codebook quarter
    const int kbase = g * CPS;

    // A fragments: 2 sets of 16 pixels; fp32 zn -> fp16 (single product)
    f16x8 ah[NSET][2];
    #pragma unroll
    for (int s = 0; s < NSET; ++s) {
        const float* zr = zn + (p0 + s * 16 + col) * EDIM;
        #pragma unroll
        for (int kc = 0; kc < 2; ++kc) {
            float f[8];
            *(float4*)(f + 0) = *(const float4*)(zr + kc * 32 + quad * 8 + 0);
            *(float4*)(f + 4) = *(const float4*)(zr + kc * 32 + quad * 8 + 4);
            #pragma unroll
            for (int i = 0; i < 8; ++i) ah[s][kc][i] = (_Float16)f[i];
        }
    }

    // top-2 state in max-space; values stuffed with 7-bit id; b1 >= b2 invariant
    float b1[NSET][4], b2[NSET][4];
    #pragma unroll
    for (int s = 0; s < NSET; ++s)
        #pragma unroll
        for (int r = 0; r < 4; ++r) { b1[s][r] = 0.0f; b2[s][r] = 0.0f; }

    const f32x4 cini = {2.0f, 2.0f, 2.0f, 2.0f};   // |z|=|e|=1 -> bias constant

    // this wave's staging window: src and dst are both uniform + lane*16
    const int combo0 = wave * 4;   // 16 combos x 1KB per 16KB stage
    const char* gsrc0 = (const char*)esw + (size_t)kbase * 128
                        + combo0 * 1024 + lane * 16;
    // prologue: issue stage 0 -> buf 0
    #pragma unroll
    for (int it = 0; it < 4; ++it)
        gload_lds16(gsrc0 + it * 1024, (char*)&es[0][0] + (combo0 + it) * 1024);

    for (int nb = 0; nb < NSTG; ++nb) {
        const int cur = nb & 1;
        __syncthreads();   // vmcnt drained: buf[cur] complete; buf[cur^1] reusable
        if (nb + 1 < NSTG) {
            const char* gsrc = gsrc0 + (size_t)(nb + 1) * (NSTAGE * EDIM * 2);
            #pragma unroll
            for (int it = 0; it < 4; ++it)
                gload_lds16(gsrc + it * 1024,
                            (char*)&es[cur ^ 1][0] + (combo0 + it) * 1024);
        }

        const short* esb = es[cur];
        #pragma unroll
        for (int sub = 0; sub < 8; ++sub) {       // 8 subtiles of 16 codes
            const short* base = esb + sub * 1024;
            const f16x8 bh0 = *(const f16x8*)(base + lane * 8);
            const f16x8 bh1 = *(const f16x8*)(base + 512 + lane * 8);
            const unsigned sid = (unsigned)((nb << 3) | sub);  // 7-bit id, uniform
            #pragma unroll
            for (int s = 0; s < NSET; ++s) {
                // 2-deep chain seeded with C = {2.0}
                f32x4 acc;
                acc = __builtin_amdgcn_mfma_f32_16x16x32_f16(ah[s][0], bh0, cini, 0, 0, 0);
                acc = __builtin_amdgcn_mfma_f32_16x16x32_f16(ah[s][1], bh1, acc, 0, 0, 0);
                #pragma unroll
                for (int r = 0; r < 4; ++r) {
                    // stuff candidate id into low mantissa bits (v_and_or_b32)
                    const float v = __uint_as_float(
                        (__float_as_uint(acc[r]) & 0xFFFFFF80u) | sid);
                    // b1>=b2 invariant -> med3 == new 2nd-max; then running max
                    b2[s][r] = __builtin_amdgcn_fmed3f(v, b2[s][r], b1[s][r]);
                    b1[s][r] = fmaxf(b1[s][r], v);
                }
            }
        }
    }

    // recover winning index from b1's stuffed id (col is lane-implicit)
    int i1[NSET][4];
    #pragma unroll
    for (int s = 0; s < NSET; ++s)
        #pragma unroll
        for (int r = 0; r < 4; ++r) {
            const unsigned id7 = __float_as_uint(b1[s][r]) & 127u;
            i1[s][r] = kbase + (int)(id7 << 4) + col;
        }

    // merge top-2 across the 16 col-lanes (xor 1,2,4,8 stays inside quad group)
    #pragma unroll
    for (int m = 1; m <= 8; m <<= 1) {
        #pragma unroll
        for (int s = 0; s < NSET; ++s)
            #pragma unroll
            for (int r = 0; r < 4; ++r) {
                const float ob1 = __shfl_xor(b1[s][r], m, 64);
                const int   oi1 = __shfl_xor(i1[s][r], m, 64);
                const float ob2 = __shfl_xor(b2[s][r], m, 64);
                const bool take = (ob1 > b1[s][r]) || (ob1 == b1[s][r] && oi1 < i1[s][r]);
                b2[s][r] = fmaxf(fmaxf(b2[s][r], ob2), fminf(b1[s][r], ob1));
                b1[s][r] = take ? ob1 : b1[s][r];
                i1[s][r] = take ? oi1 : i1[s][r];
            }
    }
    if (col == 0) {
        #pragma unroll
        for (int s = 0; s < NSET; ++s)
            #pragma unroll
            for (int r = 0; r < 4; ++r) {
                const int p = p0 + s * 16 + quad * 4 + r;   // C/D row = quad*4 + r
                pv[g * NPIX + p] = make_float2(b1[s][r], b2[s][r]);
                pi[g * NPIX + p] = (unsigned)i1[s][r];
            }
    }
}

// ---------------- merge: combine splits; rescore shortlist; enqueue suspects -
// thr = gb1 - MARGIN1. gb2 < thr -> unflagged fast path (gi1). Else: exact
// fp32 rescore of the shortlist {i1[g] : b1[g] >= thr}. If no split's
// b2 >= thr the shortlist is complete -> final. Else seed packed[p] with the
// shortlist key and enqueue 4 (pixel, 512-chunk) entries per suspect split
// (b2 >= thr); k_recheck atomicMins the exact scan of those chunks.
__global__ __launch_bounds__(256) void k_merge(const float2* __restrict__ pv,
                                               const unsigned* __restrict__ pi,
                                               const float* __restrict__ zn,
                                               const float* __restrict__ e_norm,
                                               const float* __restrict__ se_half,
                                               unsigned* __restrict__ idx_arr,
                                               unsigned* __restrict__ list2,
                                               unsigned* __restrict__ counter,
                                               unsigned long long* __restrict__ packed) {
    const int p = blockIdx.x * 256 + threadIdx.x;
    float2 v[KSPLIT]; unsigned ix[KSPLIT];
    #pragma unroll
    for (int gg = 0; gg < KSPLIT; ++gg) {
        v[gg] = pv[gg * NPIX + p];
        ix[gg] = pi[gg * NPIX + p];
    }
    // global noisy top-1 (ascending g + strict > == first-occurrence)
    float gb1 = v[0].x; unsigned gi1 = ix[0]; int win = 0;
    #pragma unroll
    for (int gg = 1; gg < KSPLIT; ++gg)
        if (v[gg].x > gb1) { gb1 = v[gg].x; gi1 = ix[gg]; win = gg; }
    float gb2 = -3.0e38f;
    #pragma unroll
    for (int gg = 0; gg < KSPLIT; ++gg) {
        gb2 = fmaxf(gb2, v[gg].y);
        if (gg != win) gb2 = fmaxf(gb2, v[gg].x);
    }
    const float thr = gb1 - MARGIN1;
    if (gb2 < thr) {                      // clear winner
        idx_arr[p] = gi1;
        return;
    }
    // exact fp32 rescore of the shortlist {i1[g] : b1[g] >= thr}
    float zr[EDIM];
    #pragma unroll
    for (int c4 = 0; c4 < 16; ++c4)
        *(float4*)(zr + c4 * 4) = *(const float4*)(zn + (size_t)p * EDIM + c4 * 4);
    float best = 3.0e38f; int bidx = 0x7FFFFFFF;
    #pragma unroll
    for (int gg = 0; gg < KSPLIT; ++gg) {
        if (v[gg].x >= thr) {
            const int c = (int)ix[gg];
            const float* er = e_norm + (size_t)c * EDIM;
            float s = 0.0f;
            #pragma unroll
            for (int k = 0; k < EDIM; ++k) s = fmaf(zr[k], er[k], s);
            const float d = se_half[c] - s;
            if (d < best || (d == best && c < bidx)) { best = d; bidx = c; }
        }
    }
    bool esc = false;
    #pragma unroll
    for (int gg = 0; gg < KSPLIT; ++gg) esc |= (v[gg].y >= thr);
    if (!esc) {                           // shortlist provably complete
        idx_arr[p] = (unsigned)bidx;
        return;
    }
    // escalate: seed with shortlist key; scan only suspect splits' chunks
    packed[p] = ((unsigned long long)order_u32(best) << 32) | (unsigned)bidx;
    idx_arr[p] = 0x80000000u | (unsigned)bidx;
    #pragma unroll
    for (int gg = 0; gg < KSPLIT; ++gg) {
        if (v[gg].y >= thr) {
            const unsigned pos = atomicAdd(&counter[0], 4u);
            if (pos + 3 < 2 * NPIX) {
                list2[pos]     = (unsigned)p | ((unsigned)(gg * 4)     << 16);
                list2[pos + 1] = (unsigned)p | ((unsigned)(gg * 4 + 1) << 16);
                list2[pos + 2] = (unsigned)p | ((unsigned)(gg * 4 + 2) << 16);
                list2[pos + 3] = (unsigned)p | ((unsigned)(gg * 4 + 3) << 16);
            }
        }
    }
}

// ---------------- tier-3: exact fp32 scan of suspect (pixel, chunk) items ----
// entry = p | (chunk << 16); chunk = 512-code block. Coalesced: 4 codes x 16
// lanes per b128 (contiguous 1KB from L2-resident e_norm); 4 independent
// shfl-reduce chains. One wave per entry, grid-strided.
__global__ __launch_bounds__(256) void k_recheck(const float* __restrict__ zn,
                                                 const float* __restrict__ e_norm,
                                                 const float* __restrict__ se_half,
                                                 const unsigned* __restrict__ list2,
                                                 const unsigned* __restrict__ counter,
                                                 unsigned long long* __restrict__ packed) {
    const int lane  = threadIdx.x & 63;
    const int k     = lane >> 4;        // code-in-group 0..3
    const int m     = lane & 15;        // c4 index 0..15
    const int wglob = (blockIdx.x * 256 + threadIdx.x) >> 6;
    const int nwav  = (gridDim.x * 256) >> 6;
    int cnt = (int)counter[0]; if (cnt > 2 * NPIX) cnt = 2 * NPIX;
    const float4* e4 = (const float4*)e_norm;

    for (int item = wglob; item < cnt; item += nwav) {
        const unsigned e = list2[item];
        const int p     = (int)(e & 0xFFFFu);
        const int chunk = (int)(e >> 16);
        const float4 zv = *(const float4*)(zn + (size_t)p * EDIM + m * 4);
        float best = 3.0e38f; int bidx = 0;
        for (int t4 = 0; t4 < 32; ++t4) {              // 16 codes per iteration
            float s[4]; int n[4];
            #pragma unroll
            for (int j = 0; j < 4; ++j) {
                n[j] = chunk * 512 + (t4 * 4 + j) * 4 + k;
                const float4 ev = e4[n[j] * 16 + m];   // lane-linear: 1KB contiguous
                s[j] = fmaf(zv.w, ev.w, fmaf(zv.z, ev.z,
                       fmaf(zv.y, ev.y, zv.x * ev.x)));
            }
            #pragma unroll
            for (int j = 0; j < 4; ++j) s[j] += __shfl_xor(s[j], 1, 64);
            #pragma unroll
            for (int j = 0; j < 4; ++j) s[j] += __shfl_xor(s[j], 2, 64);
            #pragma unroll
            for (int j = 0; j < 4; ++j) s[j] += __shfl_xor(s[j], 4, 64);
            #pragma unroll
            for (int j = 0; j < 4; ++j) s[j] += __shfl_xor(s[j], 8, 64);
            #pragma unroll
            for (int j = 0; j < 4; ++j) {              // codes ascend over (t4,j)
                const float d = se_half[n[j]] - s[j];
                if (d < best) { best = d; bidx = n[j]; }
            }
        }
        #pragma unroll
        for (int mm = 1; mm <= 32; mm <<= 1) {         // wave first-min
            const float ob = __shfl_xor(best, mm, 64);
            const int   oi = __shfl_xor(bidx, mm, 64);
            if (ob < best || (ob == best && oi < bidx)) { best = ob; bidx = oi; }
        }
        if (lane == 0) {
            const unsigned long long key =
                ((unsigned long long)order_u32(best) << 32) | (unsigned)bidx;
            atomicMin(&packed[p], key);
        }
    }
}

// ---------------- finalize: write indices + gather z_q (4 thr/pixel) ---------
__global__ __launch_bounds__(256) void k_finalize(const unsigned* __restrict__ idx_arr,
                                                  const unsigned long long* __restrict__ packed,
                                                  const float* __restrict__ e_norm,
                                                  float* __restrict__ out) {
    const int pl = threadIdx.x & 63;
    const int q  = threadIdx.x >> 6;                  // channel quarter 0..3
    const int p  = blockIdx.x * 64 + pl;
    const unsigned v = idx_arr[p];
    const int bidx = (v & 0x80000000u) ? (int)(packed[p] & 0xFFFFFFFFull)
                                       : (int)v;
    if (q == 0) out[NPIX * EDIM + p] = (float)bidx;
    const int b = p >> 12, hw = p & (HW - 1);
    float* op = out + b * (EDIM * HW) + hw;
    const float4* ep4 = (const float4*)(e_norm + (size_t)bidx * EDIM + q * 16);
    #pragma unroll
    for (int j = 0; j < 4; ++j) {
        const float4 e = ep4[j];
        const int c = q * 16 + j * 4;
        op[(c + 0) * HW] = e.x; op[(c + 1) * HW] = e.y;   // coalesced per c
        op[(c + 2) * HW] = e.z; op[(c + 3) * HW] = e.w;
    }
}

extern "C" void kernel_launch(void* const* d_in, const int* in_sizes, int n_in,
                              void* d_out, int out_size, void* d_ws, size_t ws_size,
                              hipStream_t stream) {
    const float* z   = (const float*)d_in[0];
    const float* emb = (const float*)d_in[1];
    float* out = (float*)d_out;

    // workspace layout (~13.8 MB)
    float* e_norm  = (float*)d_ws;                       // 2 MB
    float* se_half = e_norm + NE * EDIM;                 // 32 KB
    short* esw = (short*)(se_half + NE);                 // 1 MB (swizzled fp16)
    float* zn = (float*)(esw + NE * EDIM);               // 8 MB
    unsigned* idx_arr = (unsigned*)(zn + NPIX * EDIM);   // 128 KB
    unsigned* list2   = idx_arr + NPIX;                  // 256 KB (suspect items)
    unsigned* counter = list2 + 2 * NPIX;                // 4 B (+pad)
    unsigned long long* packed = (unsigned long long*)(counter + 64); // 256 KB
    float2*   pv = (float2*)(packed + NPIX);             // 1 MB
    unsigned* pi = (unsigned*)(pv + KSPLIT * NPIX);      // 512 KB

    k_prep<<<NE / 4 + NPIX / 256, 256, 0, stream>>>(emb, z, e_norm, se_half,
                                                    esw, zn, counter);
    k_mfma<<<dim3(NPIX / 128, KSPLIT), 256, 0, stream>>>(zn, esw, pv, pi);
    k_merge<<<NPIX / 256, 256, 0, stream>>>(pv, pi, zn, e_norm, se_half,
                                            idx_arr, list2, counter, packed);
    k_recheck<<<1024, 256, 0, stream>>>(zn, e_norm, se_half, list2, counter, packed);
    k_finalize<<<NPIX / 64, 256, 0, stream>>>(idx_arr, packed, e_norm, out);
}

// Round 18
// 157.115 us; speedup vs baseline: 1.1470x; 1.0369x over previous
//
#include <hip/hip_runtime.h>

// VectorQuantizer: z [8,64,64,64] fp32 (BCHW), embedding [8192,64] fp32.
// Outputs (concat): z_q [8,64,64,64] fp32 (BCHW), indices [32768] as fp32.
//
// R31: 512-thread k_mfma blocks (8 waves share one stage pair).
// R30 post-mortem: KSPLIT 8->4 left k_mfma at 75.5us -> it is steady-state
// latency-bound, not fixed-cost-bound. Pipe floors (MFMA ~14, VALU ~10,
// LDS ~10-20us) are all << 75.5; OccupancyPercent ~33% (~2.6 blocks/CU =
// ~10.5 waves) despite LDS/VGPR allowing more. Fix: 8 waves per block share
// the same 2x16KB stage double-buffer -> per-CU resident waves per barrier
// group doubles (ceiling min(LDS 5, threads 4) = 4 blocks x 8 = 32 waves).
// Per-wave work unchanged (32 px, full stage read, 2 staging combos/wave);
// total LDS/MFMA/VALU invariant; grid 512 blocks.
// Tier structure (R30, best=162.9us): KSPLIT=4, 7-bit mantissa id,
// b2-completeness shortlist in k_merge, suspect-split 512-code chunk scans,
// finalize gather. Tier-1 core otherwise R19-proven.
// Staging (R12): global_load_lds 16B registerless from pre-swizzled codebook.

#define NPIX 32768
#define NE   8192
#define EDIM 64
#define HW   4096
#define NSTAGE 128          // codes per LDS stage (8 subtiles of 16)
#define KSPLIT 4
#define CPS  (NE / KSPLIT)  // 2048 codes per split
#define NSTG (CPS / NSTAGE) // 16 stages per block
#define MARGIN1 6.0e-4f
#define NSET 2              // row-sets of 16 pixels per wave (PPW=32)

typedef _Float16 f16x8 __attribute__((ext_vector_type(8)));
typedef float f32x4  __attribute__((ext_vector_type(4)));

__device__ __forceinline__ short f2h_bits(float x) {
    _Float16 h = (_Float16)x;
    short s; __builtin_memcpy(&s, &h, 2); return s;
}
// map float to unsigned with same total order
__device__ __forceinline__ unsigned int order_u32(float f) {
    unsigned int s = __float_as_uint(f);
    return (s & 0x80000000u) ? ~s : (s | 0x80000000u);
}
// async global->LDS, 16B/lane; HW writes lane i at lds_base + i*16 (wave-uniform base)
__device__ __forceinline__ void gload_lds16(const void* g, void* l) {
    __builtin_amdgcn_global_load_lds(
        (const __attribute__((address_space(1))) void*)g,
        (__attribute__((address_space(3))) void*)l, 16, 0, 0);
}

// ---------------- prep (fused): codebook (swizzled fp16) + pixels ------------
// esw layout: per 64-code group, 8 combos (sub[4] x {k0,k1}) x 1KB; within
// combo, MFMA-B fragment order: slot frag_lane=(o&3)*16+code_col holds 8
// channels (16B). A 128-code stage = two consecutive groups (16KB).
__global__ __launch_bounds__(256) void k_prep(const float* __restrict__ emb,
                                              const float* __restrict__ z,
                                              float* __restrict__ e_norm,
                                              float* __restrict__ se_half,
                                              short* __restrict__ esw,
                                              float* __restrict__ zn,
                                              unsigned* __restrict__ counter) {
    if (blockIdx.x == 0 && threadIdx.x == 0) counter[0] = 0u;
    if (blockIdx.x < NE / 4) {
        // --- codebook: 1 code per wave, lane = channel ---
        const int wave = threadIdx.x >> 6;
        const int lane = threadIdx.x & 63;
        const int n = blockIdx.x * 4 + wave;
        float v = emb[n * EDIM + lane];
        float ss = v * v;
        #pragma unroll
        for (int off = 32; off; off >>= 1) ss += __shfl_xor(ss, off, 64);
        const float inv = 1.0f / fmaxf(sqrtf(ss), 1e-12f);
        const float en = v * inv;
        e_norm[n * EDIM + lane] = en;
        // swizzled fp16 write (c = lane)
        const int grp = n >> 6, cs = n & 63;
        const int sub = cs >> 4, colb = cs & 15;
        const int o = lane >> 3, j = lane & 7;     // o: khalf=o>>2, quad=o&3
        const int slot = ((o & 3) * 16 + colb) * 8 + j;
        esw[grp * 4096 + (sub * 2 + (o >> 2)) * 512 + slot] = f2h_bits(en);
        float s2 = en * en;
        #pragma unroll
        for (int off = 32; off; off >>= 1) s2 += __shfl_xor(s2, off, 64);
        if (lane == 0) se_half[n] = 0.5f * s2;
    } else {
        // --- pixels: single-pass normalize -> zn fp32 row-major [p][c] ---
        const int p = (blockIdx.x - NE / 4) * 256 + threadIdx.x;
        const int b = p >> 12, hw = p & (HW - 1);
        const float* zp = z + b * (EDIM * HW) + hw;
        float v[EDIM];
        #pragma unroll
        for (int c = 0; c < EDIM; ++c) v[c] = zp[c * HW];
        float ss = 0.0f;
        #pragma unroll
        for (int c = 0; c < EDIM; ++c) ss = fmaf(v[c], v[c], ss);
        const float inv = 1.0f / fmaxf(sqrtf(ss), 1e-12f);
        #pragma unroll
        for (int c4 = 0; c4 < 16; ++c4) {
            float4 o;
            o.x = v[c4 * 4 + 0] * inv;
            o.y = v[c4 * 4 + 1] * inv;
            o.z = v[c4 * 4 + 2] * inv;
            o.w = v[c4 * 4 + 3] * inv;
            *(float4*)(zn + p * EDIM + c4 * 4) = o;
        }
    }
}

// ---------------- tier-1 k_mfma: split-K partial top-2, 8-wave blocks -------
// Block: 8 waves x 32 pixels = 256 pixels, one codebook quarter (blockIdx.y).
// v = dot + 2 in [1,3]; argmin dist == argmax v (unit vectors). Low 7 mantissa
// bits carry the candidate id (stage*8+sub, 16 stages). Layouts (HW-verified):
// A[m=lane&15][k=quad*8+j], B[k=quad*8+j][n=lane&15], C/D row=(lane>>4)*4+reg,
// col=lane&15.
__global__ __launch_bounds__(512, 1) void k_mfma(const float* __restrict__ zn,
                                                 const short* __restrict__ esw,
                                                 float2* __restrict__ pv,   // [g][p] {b1,b2} (max-space)
                                                 unsigned* __restrict__ pi) // [g][p] i1
{
    __shared__ __align__(16) short es[2][NSTAGE * EDIM];   // 2 x 16KB

    const int tid  = threadIdx.x;             // 0..511
    const int wave = tid >> 6, lane = tid & 63;
    const int quad = lane >> 4, col = lane & 15;
    const int p0   = blockIdx.x * 256 + wave * 32;  // wave's 32 pixels (2 sets)
    const int g    = blockIdx.y;                    // codebook quarter
    const int kbase = g * CPS;

    // A fragments: 2 sets of 16 pixels; fp32 zn -> fp16 (single product)
    f16x8 ah[NSET][2];
    #pragma unroll
    for (int s = 0; s < NSET; ++s) {
        const float* zr = zn + (p0 + s * 16 + col) * EDIM;
        #pragma unroll
        for (int kc = 0; kc < 2; ++kc) {
            float f[8];
            *(float4*)(f + 0) = *(const float4*)(zr + kc * 32 + quad * 8 + 0);
            *(float4*)(f + 4) = *(const float4*)(zr + kc * 32 + quad * 8 + 4);
            #pragma unroll
            for (int i = 0; i < 8; ++i) ah[s][kc][i] = (_Float16)f[i];
        }
    }

    // top-2 state in max-space; values stuffed with 7-bit id; b1 >= b2 invariant
    float b1[NSET][4], b2[NSET][4];
    #pragma unroll
    for (int s = 0; s < NSET; ++s)
        #pragma unroll
        for (int r = 0; r < 4; ++r) { b1[s][r] = 0.0f; b2[s][r] = 0.0f; }

    const f32x4 cini = {2.0f, 2.0f, 2.0f, 2.0f};   // |z|=|e|=1 -> bias constant

    // staging: 16 combos x 1KB per 16KB stage, 2 combos per wave (8 waves)
    const int combo0 = wave * 2;
    const char* gsrc0 = (const char*)esw + (size_t)kbase * 128
                        + combo0 * 1024 + lane * 16;
    // prologue: issue stage 0 -> buf 0
    #pragma unroll
    for (int it = 0; it < 2; ++it)
        gload_lds16(gsrc0 + it * 1024, (char*)&es[0][0] + (combo0 + it) * 1024);

    for (int nb = 0; nb < NSTG; ++nb) {
        const int cur = nb & 1;
        __syncthreads();   // vmcnt drained: buf[cur] complete; buf[cur^1] reusable
        if (nb + 1 < NSTG) {
            const char* gsrc = gsrc0 + (size_t)(nb + 1) * (NSTAGE * EDIM * 2);
            #pragma unroll
            for (int it = 0; it < 2; ++it)
                gload_lds16(gsrc + it * 1024,
                            (char*)&es[cur ^ 1][0] + (combo0 + it) * 1024);
        }

        const short* esb = es[cur];
        #pragma unroll
        for (int sub = 0; sub < 8; ++sub) {       // 8 subtiles of 16 codes
            const short* base = esb + sub * 1024;
            const f16x8 bh0 = *(const f16x8*)(base + lane * 8);
            const f16x8 bh1 = *(const f16x8*)(base + 512 + lane * 8);
            const unsigned sid = (unsigned)((nb << 3) | sub);  // 7-bit id, uniform
            #pragma unroll
            for (int s = 0; s < NSET; ++s) {
                // 2-deep chain seeded with C = {2.0}
                f32x4 acc;
                acc = __builtin_amdgcn_mfma_f32_16x16x32_f16(ah[s][0], bh0, cini, 0, 0, 0);
                acc = __builtin_amdgcn_mfma_f32_16x16x32_f16(ah[s][1], bh1, acc, 0, 0, 0);
                #pragma unroll
                for (int r = 0; r < 4; ++r) {
                    // stuff candidate id into low mantissa bits (v_and_or_b32)
                    const float v = __uint_as_float(
                        (__float_as_uint(acc[r]) & 0xFFFFFF80u) | sid);
                    // b1>=b2 invariant -> med3 == new 2nd-max; then running max
                    b2[s][r] = __builtin_amdgcn_fmed3f(v, b2[s][r], b1[s][r]);
                    b1[s][r] = fmaxf(b1[s][r], v);
                }
            }
        }
    }

    // recover winning index from b1's stuffed id (col is lane-implicit)
    int i1[NSET][4];
    #pragma unroll
    for (int s = 0; s < NSET; ++s)
        #pragma unroll
        for (int r = 0; r < 4; ++r) {
            const unsigned id7 = __float_as_uint(b1[s][r]) & 127u;
            i1[s][r] = kbase + (int)(id7 << 4) + col;
        }

    // merge top-2 across the 16 col-lanes (xor 1,2,4,8 stays inside quad group)
    #pragma unroll
    for (int m = 1; m <= 8; m <<= 1) {
        #pragma unroll
        for (int s = 0; s < NSET; ++s)
            #pragma unroll
            for (int r = 0; r < 4; ++r) {
                const float ob1 = __shfl_xor(b1[s][r], m, 64);
                const int   oi1 = __shfl_xor(i1[s][r], m, 64);
                const float ob2 = __shfl_xor(b2[s][r], m, 64);
                const bool take = (ob1 > b1[s][r]) || (ob1 == b1[s][r] && oi1 < i1[s][r]);
                b2[s][r] = fmaxf(fmaxf(b2[s][r], ob2), fminf(b1[s][r], ob1));
                b1[s][r] = take ? ob1 : b1[s][r];
                i1[s][r] = take ? oi1 : i1[s][r];
            }
    }
    if (col == 0) {
        #pragma unroll
        for (int s = 0; s < NSET; ++s)
            #pragma unroll
            for (int r = 0; r < 4; ++r) {
                const int p = p0 + s * 16 + quad * 4 + r;   // C/D row = quad*4 + r
                pv[g * NPIX + p] = make_float2(b1[s][r], b2[s][r]);
                pi[g * NPIX + p] = (unsigned)i1[s][r];
            }
    }
}

// ---------------- merge: combine splits; rescore shortlist; enqueue suspects -
// thr = gb1 - MARGIN1. gb2 < thr -> unflagged fast path (gi1). Else: exact
// fp32 rescore of the shortlist {i1[g] : b1[g] >= thr}. If no split's
// b2 >= thr the shortlist is complete -> final. Else seed packed[p] with the
// shortlist key and enqueue 4 (pixel, 512-chunk) entries per suspect split
// (b2 >= thr); k_recheck atomicMins the exact scan of those chunks.
__global__ __launch_bounds__(256) void k_merge(const float2* __restrict__ pv,
                                               const unsigned* __restrict__ pi,
                                               const float* __restrict__ zn,
                                               const float* __restrict__ e_norm,
                                               const float* __restrict__ se_half,
                                               unsigned* __restrict__ idx_arr,
                                               unsigned* __restrict__ list2,
                                               unsigned* __restrict__ counter,
                                               unsigned long long* __restrict__ packed) {
    const int p = blockIdx.x * 256 + threadIdx.x;
    float2 v[KSPLIT]; unsigned ix[KSPLIT];
    #pragma unroll
    for (int gg = 0; gg < KSPLIT; ++gg) {
        v[gg] = pv[gg * NPIX + p];
        ix[gg] = pi[gg * NPIX + p];
    }
    // global noisy top-1 (ascending g + strict > == first-occurrence)
    float gb1 = v[0].x; unsigned gi1 = ix[0]; int win = 0;
    #pragma unroll
    for (int gg = 1; gg < KSPLIT; ++gg)
        if (v[gg].x > gb1) { gb1 = v[gg].x; gi1 = ix[gg]; win = gg; }
    float gb2 = -3.0e38f;
    #pragma unroll
    for (int gg = 0; gg < KSPLIT; ++gg) {
        gb2 = fmaxf(gb2, v[gg].y);
        if (gg != win) gb2 = fmaxf(gb2, v[gg].x);
    }
    const float thr = gb1 - MARGIN1;
    if (gb2 < thr) {                      // clear winner
        idx_arr[p] = gi1;
        return;
    }
    // exact fp32 rescore of the shortlist {i1[g] : b1[g] >= thr}
    float zr[EDIM];
    #pragma unroll
    for (int c4 = 0; c4 < 16; ++c4)
        *(float4*)(zr + c4 * 4) = *(const float4*)(zn + (size_t)p * EDIM + c4 * 4);
    float best = 3.0e38f; int bidx = 0x7FFFFFFF;
    #pragma unroll
    for (int gg = 0; gg < KSPLIT; ++gg) {
        if (v[gg].x >= thr) {
            const int c = (int)ix[gg];
            const float* er = e_norm + (size_t)c * EDIM;
            float s = 0.0f;
            #pragma unroll
            for (int k = 0; k < EDIM; ++k) s = fmaf(zr[k], er[k], s);
            const float d = se_half[c] - s;
            if (d < best || (d == best && c < bidx)) { best = d; bidx = c; }
        }
    }
    bool esc = false;
    #pragma unroll
    for (int gg = 0; gg < KSPLIT; ++gg) esc |= (v[gg].y >= thr);
    if (!esc) {                           // shortlist provably complete
        idx_arr[p] = (unsigned)bidx;
        return;
    }
    // escalate: seed with shortlist key; scan only suspect splits' chunks
    packed[p] = ((unsigned long long)order_u32(best) << 32) | (unsigned)bidx;
    idx_arr[p] = 0x80000000u | (unsigned)bidx;
    #pragma unroll
    for (int gg = 0; gg < KSPLIT; ++gg) {
        if (v[gg].y >= thr) {
            const unsigned pos = atomicAdd(&counter[0], 4u);
            if (pos + 3 < 2 * NPIX) {
                list2[pos]     = (unsigned)p | ((unsigned)(gg * 4)     << 16);
                list2[pos + 1] = (unsigned)p | ((unsigned)(gg * 4 + 1) << 16);
                list2[pos + 2] = (unsigned)p | ((unsigned)(gg * 4 + 2) << 16);
                list2[pos + 3] = (unsigned)p | ((unsigned)(gg * 4 + 3) << 16);
            }
        }
    }
}

// ---------------- tier-3: exact fp32 scan of suspect (pixel, chunk) items ----
// entry = p | (chunk << 16); chunk = 512-code block. Coalesced: 4 codes x 16
// lanes per b128 (contiguous 1KB from L2-resident e_norm); 4 independent
// shfl-reduce chains. One wave per entry, grid-strided.
__global__ __launch_bounds__(256) void k_recheck(const float* __restrict__ zn,
                                                 const float* __restrict__ e_norm,
                                                 const float* __restrict__ se_half,
                                                 const unsigned* __restrict__ list2,
                                                 const unsigned* __restrict__ counter,
                                                 unsigned long long* __restrict__ packed) {
    const int lane  = threadIdx.x & 63;
    const int k     = lane >> 4;        // code-in-group 0..3
    const int m     = lane & 15;        // c4 index 0..15
    const int wglob = (blockIdx.x * 256 + threadIdx.x) >> 6;
    const int nwav  = (gridDim.x * 256) >> 6;
    int cnt = (int)counter[0]; if (cnt > 2 * NPIX) cnt = 2 * NPIX;
    const float4* e4 = (const float4*)e_norm;

    for (int item = wglob; item < cnt; item += nwav) {
        const unsigned e = list2[item];
        const int p     = (int)(e & 0xFFFFu);
        const int chunk = (int)(e >> 16);
        const float4 zv = *(const float4*)(zn + (size_t)p * EDIM + m * 4);
        float best = 3.0e38f; int bidx = 0;
        for (int t4 = 0; t4 < 32; ++t4) {              // 16 codes per iteration
            float s[4]; int n[4];
            #pragma unroll
            for (int j = 0; j < 4; ++j) {
                n[j] = chunk * 512 + (t4 * 4 + j) * 4 + k;
                const float4 ev = e4[n[j] * 16 + m];   // lane-linear: 1KB contiguous
                s[j] = fmaf(zv.w, ev.w, fmaf(zv.z, ev.z,
                       fmaf(zv.y, ev.y, zv.x * ev.x)));
            }
            #pragma unroll
            for (int j = 0; j < 4; ++j) s[j] += __shfl_xor(s[j], 1, 64);
            #pragma unroll
            for (int j = 0; j < 4; ++j) s[j] += __shfl_xor(s[j], 2, 64);
            #pragma unroll
            for (int j = 0; j < 4; ++j) s[j] += __shfl_xor(s[j], 4, 64);
            #pragma unroll
            for (int j = 0; j < 4; ++j) s[j] += __shfl_xor(s[j], 8, 64);
            #pragma unroll
            for (int j = 0; j < 4; ++j) {              // codes ascend over (t4,j)
                const float d = se_half[n[j]] - s[j];
                if (d < best) { best = d; bidx = n[j]; }
            }
        }
        #pragma unroll
        for (int mm = 1; mm <= 32; mm <<= 1) {         // wave first-min
            const float ob = __shfl_xor(best, mm, 64);
            const int   oi = __shfl_xor(bidx, mm, 64);
            if (ob < best || (ob == best && oi < bidx)) { best = ob; bidx = oi; }
        }
        if (lane == 0) {
            const unsigned long long key =
                ((unsigned long long)order_u32(best) << 32) | (unsigned)bidx;
            atomicMin(&packed[p], key);
        }
    }
}

// ---------------- finalize: write indices + gather z_q (4 thr/pixel) ---------
__global__ __launch_bounds__(256) void k_finalize(const unsigned* __restrict__ idx_arr,
                                                  const unsigned long long* __restrict__ packed,
                                                  const float* __restrict__ e_norm,
                                                  float* __restrict__ out) {
    const int pl = threadIdx.x & 63;
    const int q  = threadIdx.x >> 6;                  // channel quarter 0..3
    const int p  = blockIdx.x * 64 + pl;
    const unsigned v = idx_arr[p];
    const int bidx = (v & 0x80000000u) ? (int)(packed[p] & 0xFFFFFFFFull)
                                       : (int)v;
    if (q == 0) out[NPIX * EDIM + p] = (float)bidx;
    const int b = p >> 12, hw = p & (HW - 1);
    float* op = out + b * (EDIM * HW) + hw;
    const float4* ep4 = (const float4*)(e_norm + (size_t)bidx * EDIM + q * 16);
    #pragma unroll
    for (int j = 0; j < 4; ++j) {
        const float4 e = ep4[j];
        const int c = q * 16 + j * 4;
        op[(c + 0) * HW] = e.x; op[(c + 1) * HW] = e.y;   // coalesced per c
        op[(c + 2) * HW] = e.z; op[(c + 3) * HW] = e.w;
    }
}

extern "C" void kernel_launch(void* const* d_in, const int* in_sizes, int n_in,
                              void* d_out, int out_size, void* d_ws, size_t ws_size,
                              hipStream_t stream) {
    const float* z   = (const float*)d_in[0];
    const float* emb = (const float*)d_in[1];
    float* out = (float*)d_out;

    // workspace layout (~13.8 MB)
    float* e_norm  = (float*)d_ws;                       // 2 MB
    float* se_half = e_norm + NE * EDIM;                 // 32 KB
    short* esw = (short*)(se_half + NE);                 // 1 MB (swizzled fp16)
    float* zn = (float*)(esw + NE * EDIM);               // 8 MB
    unsigned* idx_arr = (unsigned*)(zn + NPIX * EDIM);   // 128 KB
    unsigned* list2   = idx_arr + NPIX;                  // 256 KB (suspect items)
    unsigned* counter = list2 + 2 * NPIX;                // 4 B (+pad)
    unsigned long long* packed = (unsigned long long*)(counter + 64); // 256 KB
    float2*   pv = (float2*)(packed + NPIX);             // 1 MB
    unsigned* pi = (unsigned*)(pv + KSPLIT * NPIX);      // 512 KB

    k_prep<<<NE / 4 + NPIX / 256, 256, 0, stream>>>(emb, z, e_norm, se_half,
                                                    esw, zn, counter);
    k_mfma<<<dim3(NPIX / 256, KSPLIT), 512, 0, stream>>>(zn, esw, pv, pi);
    k_merge<<<NPIX / 256, 256, 0, stream>>>(pv, pi, zn, e_norm, se_half,
                                            idx_arr, list2, counter, packed);
    k_recheck<<<1024, 256, 0, stream>>>(zn, e_norm, se_half, list2, counter, packed);
    k_finalize<<<NPIX / 64, 256, 0, stream>>>(idx_arr, packed, e_norm, out);
}